// Round 1
// baseline (274.376 us; speedup 1.0000x reference)
//
#include <hip/hip_runtime.h>
#include <stdint.h>

// ---------------------------------------------------------------------------
// EmbraceNet fused: out[b,e] = relu(x_f @ W_f + b_f)[b,e],  f = idx[b,e]
// idx = categorical(key=42): partitionable threefry, bits = y0^y1 of
// threefry2x32((0,42), (0, (e*4096+b)*4+f)); argmax over bits>>9, strict >.
// PASS since R4 (absmax 0.031).
//
// R11: gemm rebuilt as counted-vmcnt deep pipeline (T3+T4 from the 8-phase
// family): BM=256 x BN=128, 512 thr / 8 waves (4Mx2N, wave tile 64x64 --
// same verified fragment/epilogue math as R10), BK=64, TRIPLE-buffered LDS
// (144 KiB, 1 block/CU), depth-2 prefetch. Per K-step: issue 6
// global_load_lds for kt+2, compute kt, then s_waitcnt vmcnt(6) + raw
// s_barrier -- prefetch stays in flight ACROSS barriers (the old
// __syncthreads drained vmcnt to 0 every step = the 30% MfmaUtil cap).
// Race analysis: buffer staged at kt (for kt+2) was last read at kt-1,
// ordered by the kt-1 barrier; vmcnt(6) drains all loads older than the 6
// just issued, which includes all of kt+1's staging (FIFO vmcnt). iw/bias
// preloaded to regs so no stray vector loads perturb the counted waits.
// Grid 16x16 = 256 blocks = 1/CU, bijective XCD-chunked swizzle (T1).
// setprio(1) around each 16-MFMA cluster (T5).
// ---------------------------------------------------------------------------

typedef short short8 __attribute__((ext_vector_type(8)));
typedef float floatx4 __attribute__((ext_vector_type(4)));

#define B_DIM 4096
#define K_DIM 1024
#define E_DIM 2048

__device__ __forceinline__ uint32_t rotl32(uint32_t x, uint32_t r) {
  return __builtin_amdgcn_alignbit(x, x, 32u - r);
}

__device__ __forceinline__ uint16_t f2bf(float x) {
  uint32_t u = __float_as_uint(x);
  u += 0x7FFFu + ((u >> 16) & 1u);
  return (uint16_t)(u >> 16);
}

// JAX threefry2x32, key = (0, 42)
__device__ __forceinline__ void threefry(uint32_t x0, uint32_t x1,
                                         uint32_t& o0, uint32_t& o1) {
  const uint32_t ks0 = 0u;
  const uint32_t ks1 = 42u;
  const uint32_t ks2 = 0x1BD11BDAu ^ 42u;
  x0 += ks0; x1 += ks1;
#define TF_R(r) { x0 += x1; x1 = rotl32(x1, r); x1 ^= x0; }
  TF_R(13) TF_R(15) TF_R(26) TF_R(6)
  x0 += ks1; x1 += ks2 + 1u;
  TF_R(17) TF_R(29) TF_R(16) TF_R(24)
  x0 += ks2; x1 += ks0 + 2u;
  TF_R(13) TF_R(15) TF_R(26) TF_R(6)
  x0 += ks0; x1 += ks1 + 3u;
  TF_R(17) TF_R(29) TF_R(16) TF_R(24)
  x0 += ks1; x1 += ks2 + 4u;
  TF_R(13) TF_R(15) TF_R(26) TF_R(6)
  x0 += ks2; x1 += ks0 + 5u;
#undef TF_R
  o0 = x0; o1 = x1;
}

// 8192 blocks x 256 threads. Every thread: issue x loads (8 floats) + W
// loads (4 floats), crunch 4 idx outputs (16 threefry) while loads fly,
// then store x bf16 (16B), idx byte, and W transposed tile via LDS.
__global__ __launch_bounds__(256) void prep_kernel(
    const float* __restrict__ x0, const float* __restrict__ x1,
    const float* __restrict__ x2, const float* __restrict__ x3,
    const float* __restrict__ W0, const float* __restrict__ W1,
    const float* __restrict__ W2, const float* __restrict__ W3,
    uint16_t* __restrict__ xb, uint16_t* __restrict__ Wt,
    uint8_t* __restrict__ idx1) {
  __shared__ float tile[32][33];
  const uint32_t g = blockIdx.x;       // 0..8191
  const int t = threadIdx.x;
  const int f = g >> 11;               // plane 0..3
  const uint32_t ip = g & 2047u;       // tile/chunk within plane

  // ---- issue x loads: plane f, 8 consecutive floats per thread ----
  const float* x = (f == 0) ? x0 : (f == 1) ? x1 : (f == 2) ? x2 : x3;
  const size_t xoff = ((size_t)ip * 256 + t) * 8;
  float4 v0 = *(const float4*)(x + xoff);
  float4 v1 = *(const float4*)(x + xoff + 4);

  // ---- issue W loads: 32x32 tile ip of plane f ----
  const float* W = (f == 0) ? W0 : (f == 1) ? W1 : (f == 2) ? W2 : W3;
  const int e0 = (int)(ip & 63) * 32, k0 = (int)(ip >> 6) * 32;
  const int tx = t & 31, ty = t >> 5;
  float wv[4];
#pragma unroll
  for (int i = 0; i < 4; ++i)
    wv[i] = W[(size_t)(k0 + ty + i * 8) * E_DIM + e0 + tx];

  // ---- threefry crunch: outputs o0..o0+3, pack 2 bits each ----
  const uint32_t o0i = (g * 256u + t) * 4u;
  uint32_t byte = 0;
#pragma unroll
  for (uint32_t q = 0; q < 4; ++q) {
    uint32_t c = (o0i + q) << 2;
    uint32_t best = 0, bi = 0;
#pragma unroll
    for (uint32_t ff = 0; ff < 4; ++ff) {
      uint32_t y0, y1;
      threefry(0u, c + ff, y0, y1);
      uint32_t m = (y0 ^ y1) >> 9;
      if (ff == 0) best = m;
      else if (m > best) { best = m; bi = ff; }
    }
    byte |= bi << (2 * q);
  }
  idx1[g * 256u + t] = (uint8_t)byte;

  // ---- x store: 8 bf16 = 16B ----
  {
    union { uint16_t h[8]; uint64_t q[2]; } p;
    p.h[0] = f2bf(v0.x); p.h[1] = f2bf(v0.y);
    p.h[2] = f2bf(v0.z); p.h[3] = f2bf(v0.w);
    p.h[4] = f2bf(v1.x); p.h[5] = f2bf(v1.y);
    p.h[6] = f2bf(v1.z); p.h[7] = f2bf(v1.w);
    uint64_t* dst = (uint64_t*)(xb + (size_t)f * B_DIM * K_DIM + xoff);
    dst[0] = p.q[0]; dst[1] = p.q[1];
  }

  // ---- W transpose via LDS ----
#pragma unroll
  for (int i = 0; i < 4; ++i) tile[ty + i * 8][tx] = wv[i];
  __syncthreads();
  {
    const int el = t >> 3, kc = (t & 7) * 4;
    union { uint16_t h[4]; uint64_t q; } p;
#pragma unroll
    for (int i = 0; i < 4; ++i) p.h[i] = f2bf(tile[kc + i][el]);
    uint16_t* dst = Wt + (size_t)f * E_DIM * K_DIM;
    *(uint64_t*)(dst + (size_t)(e0 + el) * K_DIM + k0 + kc) = p.q;
  }
}

__device__ __forceinline__ void async16(const uint16_t* g, uint16_t* lds) {
  __builtin_amdgcn_global_load_lds(
      (const __attribute__((address_space(1))) void*)g,
      (__attribute__((address_space(3))) void*)lds, 16, 0, 0);
}

#define PLANE_A ((size_t)B_DIM * K_DIM)
#define PLANE_B ((size_t)E_DIM * K_DIM)

// 512 threads (8 waves as 4Mx2N of 64x64), BM=256 x BN=128 tile, BK=64,
// flat 64-K-step loop (f = kt>>4), triple-buffered LDS (144 KiB), depth-2
// prefetch with counted vmcnt. LDS[row][pos] holds global k-chunk
// pos^(row&7) (XOR swizzle, 8x16B chunks) -- same scheme as R10 (0 bank
// conflicts measured).
__global__ __launch_bounds__(512, 2) void gemm_fused(
    const uint16_t* __restrict__ Ab, const uint16_t* __restrict__ Bbt,
    const uint32_t* __restrict__ idx2,
    const float* __restrict__ bias0, const float* __restrict__ bias1,
    const float* __restrict__ bias2, const float* __restrict__ bias3,
    float* __restrict__ out) {
  __shared__ uint16_t As[3][256 * 64];   // 96 KiB
  __shared__ uint16_t Bs[3][128 * 64];   // 48 KiB

  const int tid = threadIdx.x;
  const int w = tid >> 6;        // 0..7
  const int l = tid & 63;

  // bijective XCD-chunked swizzle: 256 blocks, 8 XCDs x 32 contiguous tiles
  const int flat = (int)(blockIdx.y * gridDim.x + blockIdx.x);
  const int swz = (flat & 7) * 32 + (flat >> 3);
  const int mBase = (swz >> 4) * 256;
  const int nBase = (swz & 15) * 128;

  const int wm = (w >> 1) * 64;  // 0,64,128,192
  const int wn = (w & 1) * 64;   // 0,64
  const int fr = l & 15, fq = l >> 4;

  // staging: lane -> row sr (of 8-row chunk), swizzled k-chunk
  const int sr = l >> 3;
  const int sgk = ((l & 7) ^ sr) * 8;
  const uint16_t* aBase = Ab + (size_t)(mBase + 32 * w + sr) * K_DIM + sgk;
  const uint16_t* bBase = Bbt + (size_t)(nBase + 16 * w + sr) * K_DIM + sgk;

  // preload selection words + bias (kept in regs so the counted vmcnt
  // stream in the main loop sees only staging loads)
  const int b_hi0 = (mBase + wm) >> 4;
  uint32_t iw[4][4];
#pragma unroll
  for (int ni = 0; ni < 4; ++ni) {
    int col = nBase + wn + ni * 16 + fr;
#pragma unroll
    for (int mi = 0; mi < 4; ++mi)
      iw[ni][mi] = idx2[(size_t)col * (B_DIM / 16) + b_hi0 + mi];
  }
  float bz0[4], bz1[4], bz2[4], bz3[4];
#pragma unroll
  for (int ni = 0; ni < 4; ++ni) {
    int col = nBase + wn + ni * 16 + fr;
    bz0[ni] = bias0[col]; bz1[ni] = bias1[col];
    bz2[ni] = bias2[col]; bz3[ni] = bias3[col];
  }

  // stage K-step t (0..63) into buffer tb: 4 A-slots + 2 B-slots per wave
  auto stage = [&](int t, int tb) {
    const int fA = t >> 4, ko = (t & 15) * 64;
    const uint16_t* pA = aBase + (size_t)fA * PLANE_A + ko;
    const uint16_t* pB = bBase + (size_t)fA * PLANE_B + ko;
#pragma unroll
    for (int tt = 0; tt < 4; ++tt)
      async16(pA + (size_t)(8 * tt) * K_DIM, &As[tb][(4 * w + tt) * 512]);
#pragma unroll
    for (int tt = 0; tt < 2; ++tt)
      async16(pB + (size_t)(8 * tt) * K_DIM, &Bs[tb][(2 * w + tt) * 512]);
  };

  floatx4 acc[4][4] = {};
  floatx4 res[4][4] = {};

  // prologue: fill buffers 0 and 1, wait only for buffer 0 (vmcnt(6)
  // leaves stage(1)'s 6 newest in flight; everything older -- iw, bias,
  // stage(0) -- is drained)
  stage(0, 0);
  stage(1, 1);
  asm volatile("s_waitcnt vmcnt(6)" ::: "memory");
  __builtin_amdgcn_s_barrier();
  asm volatile("" ::: "memory");

  int cb = 0, tb = 2;
#pragma unroll 1
  for (int kt = 0; kt < 64; ++kt) {
    if (kt + 2 < 64) stage(kt + 2, tb);

#pragma unroll
    for (int h = 0; h < 2; ++h) {
      short8 a[4], b[4];
      const int ch = h * 4 + fq;
      const int kc = (ch ^ (fr & 7)) * 8;
#pragma unroll
      for (int mi = 0; mi < 4; ++mi)
        a[mi] = *(const short8*)&As[cb][(wm + mi * 16 + fr) * 64 + kc];
#pragma unroll
      for (int ni = 0; ni < 4; ++ni)
        b[ni] = *(const short8*)&Bs[cb][(wn + ni * 16 + fr) * 64 + kc];
      __builtin_amdgcn_s_setprio(1);
#pragma unroll
      for (int mi = 0; mi < 4; ++mi)
#pragma unroll
        for (int ni = 0; ni < 4; ++ni)
          acc[mi][ni] = __builtin_amdgcn_mfma_f32_16x16x32_bf16(
              a[mi], b[ni], acc[mi][ni], 0, 0, 0);
      __builtin_amdgcn_s_setprio(0);
    }

    // f-boundary: fold this plane's acc into res where selected, reset acc
    if ((kt & 15) == 15) {
      const int f = kt >> 4;
#pragma unroll
      for (int ni = 0; ni < 4; ++ni) {
        float bv = (f == 0) ? bz0[ni] : (f == 1) ? bz1[ni]
                 : (f == 2) ? bz2[ni] : bz3[ni];
#pragma unroll
        for (int mi = 0; mi < 4; ++mi) {
          uint32_t wd = iw[ni][mi];
#pragma unroll
          for (int r = 0; r < 4; ++r) {
            uint32_t sel = (wd >> (2 * (fq * 4 + r))) & 3u;
            if (sel == (uint32_t)f) res[mi][ni][r] = acc[mi][ni][r] + bv;
            acc[mi][ni][r] = 0.f;
          }
        }
      }
    }

    // counted wait: >=6 oldest complete => all of kt+1's staging landed.
    // Only the last two iterations drain fully.
    if (kt < 62) {
      asm volatile("s_waitcnt vmcnt(6)" ::: "memory");
      __builtin_amdgcn_s_barrier();
      asm volatile("" ::: "memory");
    } else if (kt < 63) {
      asm volatile("s_waitcnt vmcnt(0)" ::: "memory");
      __builtin_amdgcn_s_barrier();
      asm volatile("" ::: "memory");
    }
    cb = (cb == 2) ? 0 : cb + 1;
    tb = (tb == 2) ? 0 : tb + 1;
  }

  // dense coalesced store with relu. C/D: col=lane&15, row=(lane>>4)*4+reg
#pragma unroll
  for (int ni = 0; ni < 4; ++ni) {
    int col = nBase + wn + ni * 16 + fr;
#pragma unroll
    for (int mi = 0; mi < 4; ++mi) {
      int row0 = mBase + wm + mi * 16 + fq * 4;
#pragma unroll
      for (int r = 0; r < 4; ++r) {
        float o = res[mi][ni][r];
        __builtin_nontemporal_store(o > 0.f ? o : 0.f,
                                    &out[(size_t)(row0 + r) * E_DIM + col]);
      }
    }
  }
}

extern "C" void kernel_launch(void* const* d_in, const int* in_sizes, int n_in,
                              void* d_out, int out_size, void* d_ws, size_t ws_size,
                              hipStream_t stream) {
  const float* x[4]; const float* W[4]; const float* bs[4];
  for (int f = 0; f < 4; ++f) {
    x[f]  = (const float*)d_in[3 * f + 0];
    W[f]  = (const float*)d_in[3 * f + 1];
    bs[f] = (const float*)d_in[3 * f + 2];
  }
  char* ws = (char*)d_ws;
  uint16_t* xb  = (uint16_t*)ws;                               // 32 MB
  uint16_t* Wt  = (uint16_t*)(ws + (size_t)32 * 1024 * 1024);  // 16 MB
  uint8_t*  idx1 = (uint8_t*)(ws + (size_t)48 * 1024 * 1024);  //  2 MB
  float* out = (float*)d_out;

  prep_kernel<<<dim3(8192), dim3(256), 0, stream>>>(
      x[0], x[1], x[2], x[3], W[0], W[1], W[2], W[3], xb, Wt, idx1);
  gemm_fused<<<dim3(E_DIM / 128, B_DIM / 256), dim3(512), 0, stream>>>(
      xb, Wt, (const uint32_t*)idx1, bs[0], bs[1], bs[2], bs[3], out);
}